// Round 15
// baseline (183.560 us; speedup 1.0000x reference)
//
#include <hip/hip_runtime.h>
#include <math.h>

#define Bv   32
#define Nv   1024
#define Dv   768
#define Cv   201
#define Kv   5
#define CKv  1005
#define BNv  32768
#define NCLS 200

// output offsets (floats)
#define OFF_CL     0
#define OFF_IPL    6400
#define OFF_LOG    38560
#define OFF_PART   32970400
#define OFF_PNEW   33003168
#define OFF_PSEUDO 33775008

typedef short bf16x8 __attribute__((ext_vector_type(8)));
typedef float f32x4  __attribute__((ext_vector_type(4)));
typedef float f32x4u __attribute__((ext_vector_type(4), aligned(4)));
typedef __attribute__((address_space(1))) const unsigned int g_u32;
typedef __attribute__((address_space(3))) unsigned int l_u32;

__device__ inline unsigned short f2bf(float f) {
  unsigned u = __float_as_uint(f);
  u += 0x7fffu + ((u >> 16) & 1u);     // RNE
  return (unsigned short)(u >> 16);
}
// order-preserving float<->uint for atomicMax
__device__ inline unsigned fenc(float f) {
  unsigned u = __float_as_uint(f);
  return u ^ (((unsigned)((int)u >> 31)) | 0x80000000u);
}
__device__ inline float fdec(unsigned u) {
  unsigned bits = (u & 0x80000000u) ? (u ^ 0x80000000u) : ~u;
  return __uint_as_float(bits);
}

// ---------------- fused: zero (leading blocks) + row norms + bf16 convert
// 4 rows per wave (12 independent loads in flight -> 4x MLP vs R14's
// 1-row/wave which ran at 30% BW, latency-bound).
// rows [0,BN): pt -> Ah; [BN,BN+1024): proto -> Bh (pad zeroed); rest: raw norms
__global__ __launch_bounds__(256) void prep_kernel(
    const float* __restrict__ pt, const float* __restrict__ raw,
    const float* __restrict__ proto,
    unsigned short* __restrict__ Ah, unsigned short* __restrict__ Bh,
    float* __restrict__ inv_raw, int* __restrict__ zbuf, int zn, int ZB) {
  if ((int)blockIdx.x < ZB) {
    int i = blockIdx.x * 256 + threadIdx.x;
    if (i < zn) zbuf[i] = 0;
    return;
  }
  const int rbase = (blockIdx.x - ZB) * 16 + (threadIdx.x >> 6) * 4;
  const int l = threadIdx.x & 63;

  if (rbase < BNv) {                     // ---- A: 4 rows, batched loads
    const float* src = pt + (size_t)rbase * Dv;
    float4 v[4][3];
#pragma unroll
    for (int r = 0; r < 4; ++r)
#pragma unroll
      for (int i = 0; i < 3; ++i)
        v[r][i] = reinterpret_cast<const float4*>(src + (size_t)r * Dv)[i * 64 + l];
    float s[4];
#pragma unroll
    for (int r = 0; r < 4; ++r)
      s[r] = v[r][0].x * v[r][0].x + v[r][0].y * v[r][0].y + v[r][0].z * v[r][0].z + v[r][0].w * v[r][0].w
           + v[r][1].x * v[r][1].x + v[r][1].y * v[r][1].y + v[r][1].z * v[r][1].z + v[r][1].w * v[r][1].w
           + v[r][2].x * v[r][2].x + v[r][2].y * v[r][2].y + v[r][2].z * v[r][2].z + v[r][2].w * v[r][2].w;
#pragma unroll
    for (int off = 32; off > 0; off >>= 1)
#pragma unroll
      for (int r = 0; r < 4; ++r) s[r] += __shfl_xor(s[r], off);
#pragma unroll
    for (int r = 0; r < 4; ++r) {
      float inv = 1.0f / fmaxf(sqrtf(s[r]), 1e-12f);
      unsigned short* dst = Ah + (size_t)(rbase + r) * Dv;
#pragma unroll
      for (int i = 0; i < 3; ++i) {
        float a0 = v[r][i].x * inv, a1 = v[r][i].y * inv;
        float a2 = v[r][i].z * inv, a3 = v[r][i].w * inv;
        *reinterpret_cast<ushort4*>(dst + i * 256 + 4 * l) =
            make_ushort4(f2bf(a0), f2bf(a1), f2bf(a2), f2bf(a3));
      }
    }
    return;
  }
  if (rbase < BNv + 1024) {              // ---- B: 4 rows, pad-aware
    const int rp0 = rbase - BNv;
    float4 v[4][3];
#pragma unroll
    for (int r = 0; r < 4; ++r) {
      int rp = rp0 + r;
      int rs = (rp < CKv) ? rp : (CKv - 1);      // clamp (discarded for pad)
      const float* src = proto + (size_t)rs * Dv;
#pragma unroll
      for (int i = 0; i < 3; ++i)
        v[r][i] = reinterpret_cast<const float4*>(src)[i * 64 + l];
    }
    float s[4];
#pragma unroll
    for (int r = 0; r < 4; ++r)
      s[r] = v[r][0].x * v[r][0].x + v[r][0].y * v[r][0].y + v[r][0].z * v[r][0].z + v[r][0].w * v[r][0].w
           + v[r][1].x * v[r][1].x + v[r][1].y * v[r][1].y + v[r][1].z * v[r][1].z + v[r][1].w * v[r][1].w
           + v[r][2].x * v[r][2].x + v[r][2].y * v[r][2].y + v[r][2].z * v[r][2].z + v[r][2].w * v[r][2].w;
#pragma unroll
    for (int off = 32; off > 0; off >>= 1)
#pragma unroll
      for (int r = 0; r < 4; ++r) s[r] += __shfl_xor(s[r], off);
#pragma unroll
    for (int r = 0; r < 4; ++r) {
      int rp = rp0 + r;
      unsigned short* dst = Bh + (size_t)rp * Dv;
      float inv = (rp < CKv) ? 1.0f / fmaxf(sqrtf(s[r]), 1e-12f) : 0.0f;
#pragma unroll
      for (int i = 0; i < 3; ++i) {
        float a0 = v[r][i].x * inv, a1 = v[r][i].y * inv;
        float a2 = v[r][i].z * inv, a3 = v[r][i].w * inv;
        ushort4 w = (rp < CKv)
            ? make_ushort4(f2bf(a0), f2bf(a1), f2bf(a2), f2bf(a3))
            : make_ushort4(0, 0, 0, 0);
        *reinterpret_cast<ushort4*>(dst + i * 256 + 4 * l) = w;
      }
    }
    return;
  }
  if (rbase < 2 * BNv + 1024) {          // ---- raw: 4 rows, norms only
    const int rr = rbase - BNv - 1024;
    const float* src = raw + (size_t)rr * Dv;
    float s[4];
#pragma unroll
    for (int r = 0; r < 4; ++r) {
      float4 v0 = reinterpret_cast<const float4*>(src + (size_t)r * Dv)[l];
      float4 v1 = reinterpret_cast<const float4*>(src + (size_t)r * Dv)[64 + l];
      float4 v2 = reinterpret_cast<const float4*>(src + (size_t)r * Dv)[128 + l];
      s[r] = v0.x * v0.x + v0.y * v0.y + v0.z * v0.z + v0.w * v0.w
           + v1.x * v1.x + v1.y * v1.y + v1.z * v1.z + v1.w * v1.w
           + v2.x * v2.x + v2.y * v2.y + v2.z * v2.z + v2.w * v2.w;
    }
#pragma unroll
    for (int off = 32; off > 0; off >>= 1)
#pragma unroll
      for (int r = 0; r < 4; ++r) s[r] += __shfl_xor(s[r], off);
    if (l == 0) {
#pragma unroll
      for (int r = 0; r < 4; ++r)
        inv_raw[rr + r] = 1.0f / fmaxf(sqrtf(s[r]), 1e-12f);
    }
  }
}

// ------------------------------------------------- MFMA 1-pass bf16 GEMM
// logits[m][n] = dot(a_hi, b_hi); fused col-max -> iplU.
// 1D grid 1024 blocks, XCD-aware decode (FETCH 99->66MB, R13-verified).
// BM=256 x BN=128, 512 thr / 8 waves, BK=32 (24 tiles), dbuf 48KB LDS;
// 2 fine phases/tile, counted vmcnt(3), setprio; LDS-repack epilogue.
#define BM 256
#define BN 128
__global__ __launch_bounds__(512) void gemm_mfma_kernel(
    const unsigned short* __restrict__ Ah, const unsigned short* __restrict__ Bh,
    float* __restrict__ Co, unsigned int* __restrict__ iplU) {
  __shared__ __align__(16) unsigned char smem[49152];
#define LA(b) ((unsigned short (*)[32])(smem + (b) * 16384))
#define LB(b) ((unsigned short (*)[32])(smem + 32768 + (b) * 8192))
  const int tid  = threadIdx.x;
  const int wid  = tid >> 6;
  const int lane = tid & 63;
  const int wm = wid >> 1, wn = wid & 1;
  // XCD swizzle: orig%8 = XCD; each XCD gets contiguous x-chunk, y fast
  const int orig = blockIdx.x;
  const int wgid = ((orig & 7) << 7) | (orig >> 3);
  const int m0 = (wgid >> 3) * BM, n0 = (wgid & 7) * BN;
  const int fr = lane & 15;
  const int q  = lane >> 4;

  f32x4 acc[4][4];
#pragma unroll
  for (int i = 0; i < 4; ++i)
#pragma unroll
    for (int j = 0; j < 4; ++j)
#pragma unroll
      for (int r = 0; r < 4; ++r) acc[i][j][r] = 0.f;

  // staging source pointers (swizzled global source, linear LDS dest).
  // 64B rows, 4 slots, involution slot ^= (row>>1)&3 on source+read
  const int ra = wid * 16 + (lane >> 2);             // 0..127
  const int sa = (lane & 3) ^ ((ra >> 1) & 3);
  const unsigned short* srcA0 = Ah + (size_t)(m0 + ra) * Dv + sa * 8;
  const unsigned short* srcA1 = Ah + (size_t)(m0 + 128 + ra) * Dv + sa * 8;
  const unsigned short* srcB0 = Bh + (size_t)(n0 + ra) * Dv + sa * 8;

#define STG_A0(buf, t) __builtin_amdgcn_global_load_lds((g_u32*)(srcA0 + (t) * 32), \
    (l_u32*)&LA(buf)[wid * 16][0], 16, 0, 0)
#define STG_A1(buf, t) __builtin_amdgcn_global_load_lds((g_u32*)(srcA1 + (t) * 32), \
    (l_u32*)&LA(buf)[128 + wid * 16][0], 16, 0, 0)
#define STG_B0(buf, t) __builtin_amdgcn_global_load_lds((g_u32*)(srcB0 + (t) * 32), \
    (l_u32*)&LB(buf)[wid * 16][0], 16, 0, 0)

  const int slotR = (q ^ ((fr >> 1) & 3)) * 8;       // const per lane

  // prologue: tile 0 into buf 0 (3 loads/wave in flight)
  STG_A0(0, 0); STG_A1(0, 0); STG_B0(0, 0);

#pragma unroll 2
  for (int t = 0; t < 24; ++t) {
    const int cur = t & 1;
    // issue all 3 next-tile loads, then counted wait (they stay in flight)
    if (t < 23) {
      STG_A0(cur ^ 1, t + 1); STG_A1(cur ^ 1, t + 1); STG_B0(cur ^ 1, t + 1);
      asm volatile("s_waitcnt vmcnt(3)" ::: "memory");
    } else {
      asm volatile("s_waitcnt vmcnt(0)" ::: "memory");
    }
    __builtin_amdgcn_s_barrier();            // all waves' tile-t stage landed
    __builtin_amdgcn_sched_barrier(0);       // pin ds_reads below barrier

    bf16x8 a[4];
#pragma unroll
    for (int ph = 0; ph < 2; ++ph) {
      // ---- phase: ds-load subtile, fence, MFMA cluster, barrier ----
      if (ph == 0) {
#pragma unroll
        for (int i = 0; i < 4; ++i)
          a[i] = *reinterpret_cast<const bf16x8*>(&LA(cur)[wm * 64 + i * 16 + fr][slotR]);
      }
      bf16x8 b0 = *reinterpret_cast<const bf16x8*>(&LB(cur)[wn * 64 + (ph * 2) * 16 + fr][slotR]);
      bf16x8 b1 = *reinterpret_cast<const bf16x8*>(&LB(cur)[wn * 64 + (ph * 2 + 1) * 16 + fr][slotR]);
      asm volatile("s_waitcnt lgkmcnt(0)" ::: "memory");
      __builtin_amdgcn_sched_barrier(0);
      __builtin_amdgcn_s_setprio(1);
#pragma unroll
      for (int i = 0; i < 4; ++i) {
        acc[i][ph * 2]     = __builtin_amdgcn_mfma_f32_16x16x32_bf16(a[i], b0, acc[i][ph * 2], 0, 0, 0);
        acc[i][ph * 2 + 1] = __builtin_amdgcn_mfma_f32_16x16x32_bf16(a[i], b1, acc[i][ph * 2 + 1], 0, 0, 0);
      }
      __builtin_amdgcn_s_setprio(0);
      __builtin_amdgcn_sched_barrier(0);
      __builtin_amdgcn_s_barrier();          // phase boundary (wave lockstep)
      __builtin_amdgcn_sched_barrier(0);
    }
  }
#undef STG_A0
#undef STG_A1
#undef STG_B0

  // ---- column-max + atomics (register-only, before LDS reuse) ----
  const int b_img = m0 >> 10;
#pragma unroll
  for (int j = 0; j < 4; ++j) {
    int n = n0 + wn * 64 + j * 16 + fr;
    bool ok = (n < CKv);
    float cmax = -INFINITY;
#pragma unroll
    for (int i = 0; i < 4; ++i)
#pragma unroll
      for (int r = 0; r < 4; ++r) cmax = fmaxf(cmax, acc[i][j][r]);
    cmax = fmaxf(cmax, __shfl_xor(cmax, 16));
    cmax = fmaxf(cmax, __shfl_xor(cmax, 32));
    if (lane < 16 && ok)
      atomicMax(&iplU[(size_t)b_img * 1024 + n], fenc(cmax));
  }

  // ---- repack through LDS -> contiguous 512B row stores ----
  float (*ebuf)[132] = (float (*)[132])smem;   // 64 rows x 132 (pad) floats
  const int r2 = lane >> 5;                    // 0/1: row within pair
  const int cl = (lane & 31) * 4;              // col (floats)
#pragma unroll
  for (int p = 0; p < 4; ++p) {
    __syncthreads();                           // WAR vs previous pass readers
    if (wm == p) {
#pragma unroll
      for (int i = 0; i < 4; ++i)
#pragma unroll
        for (int j = 0; j < 4; ++j)
#pragma unroll
          for (int r = 0; r < 4; ++r)
            ebuf[i * 16 + q * 4 + r][wn * 64 + j * 16 + fr] = acc[i][j][r];
    }
    __syncthreads();
#pragma unroll
    for (int rr = 0; rr < 8; rr += 2) {
      int row = wid * 8 + rr + r2;
      f32x4 v = *reinterpret_cast<const f32x4*>(&ebuf[row][cl]);
      int gc = n0 + cl;
      size_t base = (size_t)(m0 + p * 64 + row) * CKv + gc;
      if (gc + 3 < CKv) {
        *reinterpret_cast<f32x4u*>(&Co[base]) = v;
      } else {
#pragma unroll
        for (int e = 0; e < 4; ++e)
          if (gc + e < CKv) Co[base + e] = v[e];
      }
    }
  }
#undef LA
#undef LB
}

// ---------- fused: per-chunk assign (inline softmax) + centroid accum + ipl
// grid (32 b, 3 d-chunks, 9): z<8 = 128-token chunks; z==8,y==0 = ipl finalize
__global__ __launch_bounds__(256) void accum_fused_kernel(
    const float* __restrict__ logits, const int* __restrict__ labels,
    const int* __restrict__ sam, const float* __restrict__ raw,
    const float* __restrict__ inv_raw, float* __restrict__ out,
    float* __restrict__ P_acc, int* __restrict__ present,
    const unsigned int* __restrict__ iplU, const float* __restrict__ sa_w) {
  const int b = blockIdx.x;
  const int y = blockIdx.y;
  const int z = blockIdx.z;
  if (z == 8) {
    if (y != 0) return;
    int c = threadIdx.x;
    if (c >= Cv) return;
    float r[Kv];
#pragma unroll
    for (int k = 0; k < Kv; ++k) {
      r[k] = fdec(iplU[(size_t)b * 1024 + c * Kv + k]);
      out[OFF_IPL + (size_t)(b * Cv + c) * Kv + k] = r[k];
    }
    if (c < NCLS) {
      float w[Kv], wm = -INFINITY;
#pragma unroll
      for (int k = 0; k < Kv; ++k) { w[k] = sa_w[c * Kv + k]; wm = fmaxf(wm, w[k]); }
      float es = 0.f;
#pragma unroll
      for (int k = 0; k < Kv; ++k) { w[k] = expf(w[k] - wm); es += w[k]; }
      float cl = 0.f;
#pragma unroll
      for (int k = 0; k < Kv; ++k) cl += r[k] * (w[k] / es * (float)Kv);
      out[OFF_CL + b * NCLS + c] = cl / 0.2f;
    }
    return;
  }

  __shared__ float As[128][Kv];
  __shared__ float Sc[128];
  __shared__ int   Ls[128];
  const int t0 = z * 128;
  if (threadIdx.x < 128) {
    int n = b * Nv + t0 + threadIdx.x;
    int lab = (sam[n] == 1) ? labels[b] : NCLS;
    const float* p = logits + (size_t)n * CKv + lab * Kv;
    float L[Kv];
#pragma unroll
    for (int k = 0; k < Kv; ++k) L[k] = p[k];
    float mv = L[0];
    int idx = 0;
#pragma unroll
    for (int k = 1; k < Kv; ++k)
      if (L[k] > mv) { mv = L[k]; idx = k; }
    float e[Kv], s = 0.f;
#pragma unroll
    for (int k = 0; k < Kv; ++k) { e[k] = expf(L[k] - mv); s += e[k]; }
    float inv = 1.0f / s;
    float scale = (inv < 0.8f) ? 0.f : inv;
#pragma unroll
    for (int k = 0; k < Kv; ++k) As[threadIdx.x][k] = e[k] * scale;
    Ls[threadIdx.x] = lab;
    Sc[threadIdx.x] = inv_raw[n];
    if (y == 0) {
      out[OFF_PSEUDO + n] = (float)lab;
      out[OFF_PART + n] = (float)(idx + lab * Kv);
      present[lab] = 1;
    }
  }
  __syncthreads();

  const int d = y * 256 + threadIdx.x;
  float accL[Kv] = {}, accB[Kv] = {};
#pragma unroll 4
  for (int t = 0; t < 128; ++t) {
    int n2 = b * Nv + t0 + t;
    float rv = raw[(size_t)n2 * Dv + d] * Sc[t];
    if (Ls[t] == NCLS) {
#pragma unroll
      for (int k = 0; k < Kv; ++k) accB[k] = fmaf(As[t][k], rv, accB[k]);
    } else {
#pragma unroll
      for (int k = 0; k < Kv; ++k) accL[k] = fmaf(As[t][k], rv, accL[k]);
    }
  }
  int lab = labels[b];
#pragma unroll
  for (int k = 0; k < Kv; ++k) atomicAdd(&P_acc[((size_t)lab * Kv + k) * Dv + d], accL[k]);
#pragma unroll
  for (int k = 0; k < Kv; ++k) atomicAdd(&P_acc[((size_t)NCLS * Kv + k) * Dv + d], accB[k]);
}

// ------------------------------------------------------------ EMA update
__global__ __launch_bounds__(256) void pnew_kernel(
    const float* __restrict__ proto, const float* __restrict__ P_acc,
    const int* __restrict__ present, float* __restrict__ out) {
  int i = blockIdx.x * 256 + threadIdx.x;
  if (i >= Cv * Kv * Dv) return;
  int c = i / (Kv * Dv);
  float p = proto[i];
  out[OFF_PNEW + i] = present[c] ? 0.999f * p + 0.001f * P_acc[i] : p;
}

// -------------------------------------------------------------- launcher
extern "C" void kernel_launch(void* const* d_in, const int* in_sizes, int n_in,
                              void* d_out, int out_size, void* d_ws, size_t ws_size,
                              hipStream_t stream) {
  const float* pt     = (const float*)d_in[0];
  const float* raw    = (const float*)d_in[1];
  const float* proto  = (const float*)d_in[2];
  const float* sa_w   = (const float*)d_in[3];
  const int*   labels = (const int*)d_in[4];
  const int*   sam    = (const int*)d_in[5];
  float* out = (float*)d_out;

  // ---- workspace layout ----
  float* A_buf   = (float*)d_ws;                           // kept for layout
  int*   tok_lab = (int*)(A_buf + (size_t)BNv * Kv);
  float* P_acc   = (float*)(tok_lab + BNv);                // 771840 f
  int*   present = (int*)(P_acc + (size_t)Cv * Kv * Dv);   // 256 i (pad)
  unsigned int* iplU = (unsigned int*)(present + 256);     // 32768 u
  float* inv_raw = (float*)(iplU + BNv);                   // 32768 f
  unsigned short* Ah = (unsigned short*)(inv_raw + BNv);   // 32768*768 us
  unsigned short* Bh = Ah + (size_t)BNv * Dv;              // 1024*768 us

  // zero region: P_acc + present + iplU (contiguous), fused into prep
  int nz = Cv * Kv * Dv + 256 + BNv;
  int ZB = (nz + 255) / 256;
  int prep_rows_blocks = (2 * BNv + 1024) / 16;

  prep_kernel<<<ZB + prep_rows_blocks, 256, 0, stream>>>(
      pt, raw, proto, Ah, Bh, inv_raw, (int*)P_acc, nz, ZB);

  gemm_mfma_kernel<<<(BNv / BM) * (1024 / BN), 512, 0, stream>>>(
      Ah, Bh, out + OFF_LOG, iplU);

  accum_fused_kernel<<<dim3(Bv, Dv / 256, 9), 256, 0, stream>>>(
      out + OFF_LOG, labels, sam, raw, inv_raw, out, P_acc, present, iplU, sa_w);

  pnew_kernel<<<(Cv * Kv * Dv + 255) / 256, 256, 0, stream>>>(
      proto, P_acc, present, out);
}

// Round 16
// 176.101 us; speedup vs baseline: 1.0424x; 1.0424x over previous
//
#include <hip/hip_runtime.h>
#include <math.h>

#define Bv   32
#define Nv   1024
#define Dv   768
#define Cv   201
#define Kv   5
#define CKv  1005
#define BNv  32768
#define NCLS 200

// output offsets (floats)
#define OFF_CL     0
#define OFF_IPL    6400
#define OFF_LOG    38560
#define OFF_PART   32970400
#define OFF_PNEW   33003168
#define OFF_PSEUDO 33775008

typedef short bf16x8 __attribute__((ext_vector_type(8)));
typedef float f32x4  __attribute__((ext_vector_type(4)));
typedef float f32x4u __attribute__((ext_vector_type(4), aligned(4)));
typedef __attribute__((address_space(1))) const unsigned int g_u32;
typedef __attribute__((address_space(3))) unsigned int l_u32;

__device__ inline unsigned short f2bf(float f) {
  unsigned u = __float_as_uint(f);
  u += 0x7fffu + ((u >> 16) & 1u);     // RNE
  return (unsigned short)(u >> 16);
}
// order-preserving float<->uint for atomicMax
__device__ inline unsigned fenc(float f) {
  unsigned u = __float_as_uint(f);
  return u ^ (((unsigned)((int)u >> 31)) | 0x80000000u);
}
__device__ inline float fdec(unsigned u) {
  unsigned bits = (u & 0x80000000u) ? (u ^ 0x80000000u) : ~u;
  return __uint_as_float(bits);
}

// ---------------- fused: zero (leading blocks) + A/B row norms + bf16 convert
// raw-norm segment moved to the GEMM dispatch's tail blocks (R16): prep's
// 96MB raw read was half its traffic, and the GEMM grid (1024 blocks,
// 3/CU -> 768-wide waves) has an idle 2/3-of-chip drain window that
// absorbs the norm work for free.
__global__ __launch_bounds__(256) void prep_kernel(
    const float* __restrict__ pt, const float* __restrict__ proto,
    unsigned short* __restrict__ Ah, unsigned short* __restrict__ Bh,
    int* __restrict__ zbuf, int zn, int ZB) {
  if ((int)blockIdx.x < ZB) {
    int i = blockIdx.x * 256 + threadIdx.x;
    if (i < zn) zbuf[i] = 0;
    return;
  }
  const int rbase = (blockIdx.x - ZB) * 16 + (threadIdx.x >> 6) * 4;
  const int l = threadIdx.x & 63;

  if (rbase < BNv) {                     // ---- A: 4 rows, batched loads
    const float* src = pt + (size_t)rbase * Dv;
    float4 v[4][3];
#pragma unroll
    for (int r = 0; r < 4; ++r)
#pragma unroll
      for (int i = 0; i < 3; ++i)
        v[r][i] = reinterpret_cast<const float4*>(src + (size_t)r * Dv)[i * 64 + l];
    float s[4];
#pragma unroll
    for (int r = 0; r < 4; ++r)
      s[r] = v[r][0].x * v[r][0].x + v[r][0].y * v[r][0].y + v[r][0].z * v[r][0].z + v[r][0].w * v[r][0].w
           + v[r][1].x * v[r][1].x + v[r][1].y * v[r][1].y + v[r][1].z * v[r][1].z + v[r][1].w * v[r][1].w
           + v[r][2].x * v[r][2].x + v[r][2].y * v[r][2].y + v[r][2].z * v[r][2].z + v[r][2].w * v[r][2].w;
#pragma unroll
    for (int off = 32; off > 0; off >>= 1)
#pragma unroll
      for (int r = 0; r < 4; ++r) s[r] += __shfl_xor(s[r], off);
#pragma unroll
    for (int r = 0; r < 4; ++r) {
      float inv = 1.0f / fmaxf(sqrtf(s[r]), 1e-12f);
      unsigned short* dst = Ah + (size_t)(rbase + r) * Dv;
#pragma unroll
      for (int i = 0; i < 3; ++i) {
        float a0 = v[r][i].x * inv, a1 = v[r][i].y * inv;
        float a2 = v[r][i].z * inv, a3 = v[r][i].w * inv;
        *reinterpret_cast<ushort4*>(dst + i * 256 + 4 * l) =
            make_ushort4(f2bf(a0), f2bf(a1), f2bf(a2), f2bf(a3));
      }
    }
    return;
  }
  if (rbase < BNv + 1024) {              // ---- B: 4 rows, pad-aware
    const int rp0 = rbase - BNv;
    float4 v[4][3];
#pragma unroll
    for (int r = 0; r < 4; ++r) {
      int rp = rp0 + r;
      int rs = (rp < CKv) ? rp : (CKv - 1);      // clamp (discarded for pad)
      const float* src = proto + (size_t)rs * Dv;
#pragma unroll
      for (int i = 0; i < 3; ++i)
        v[r][i] = reinterpret_cast<const float4*>(src)[i * 64 + l];
    }
    float s[4];
#pragma unroll
    for (int r = 0; r < 4; ++r)
      s[r] = v[r][0].x * v[r][0].x + v[r][0].y * v[r][0].y + v[r][0].z * v[r][0].z + v[r][0].w * v[r][0].w
           + v[r][1].x * v[r][1].x + v[r][1].y * v[r][1].y + v[r][1].z * v[r][1].z + v[r][1].w * v[r][1].w
           + v[r][2].x * v[r][2].x + v[r][2].y * v[r][2].y + v[r][2].z * v[r][2].z + v[r][2].w * v[r][2].w;
#pragma unroll
    for (int off = 32; off > 0; off >>= 1)
#pragma unroll
      for (int r = 0; r < 4; ++r) s[r] += __shfl_xor(s[r], off);
#pragma unroll
    for (int r = 0; r < 4; ++r) {
      int rp = rp0 + r;
      unsigned short* dst = Bh + (size_t)rp * Dv;
      float inv = (rp < CKv) ? 1.0f / fmaxf(sqrtf(s[r]), 1e-12f) : 0.0f;
#pragma unroll
      for (int i = 0; i < 3; ++i) {
        float a0 = v[r][i].x * inv, a1 = v[r][i].y * inv;
        float a2 = v[r][i].z * inv, a3 = v[r][i].w * inv;
        ushort4 w = (rp < CKv)
            ? make_ushort4(f2bf(a0), f2bf(a1), f2bf(a2), f2bf(a3))
            : make_ushort4(0, 0, 0, 0);
        *reinterpret_cast<ushort4*>(dst + i * 256 + 4 * l) = w;
      }
    }
    return;
  }
}

// ------------------------------------------------- MFMA 1-pass bf16 GEMM
// blocks [0,1024): GEMM. logits[m][n] = dot(a_hi, b_hi); col-max -> iplU.
// blocks [1024,1280): raw-row-norm tail blocks (dispatched LAST -> run in
// the GEMM's drain window; R12 showed norm-first interferes, norm-last
// harvests the idle tail).
// GEMM: XCD-aware decode, BM=256 x BN=128, 512 thr / 8 waves, BK=32,
// dbuf 48KB LDS; 2 fine phases/tile, counted vmcnt(3), setprio;
// LDS-repack epilogue (512B row stores).
#define BM 256
#define BN 128
__global__ __launch_bounds__(512) void gemm_mfma_kernel(
    const unsigned short* __restrict__ Ah, const unsigned short* __restrict__ Bh,
    const float* __restrict__ raw, float* __restrict__ inv_raw,
    float* __restrict__ Co, unsigned int* __restrict__ iplU) {
  __shared__ __align__(16) unsigned char smem[49152];
#define LA(b) ((unsigned short (*)[32])(smem + (b) * 16384))
#define LB(b) ((unsigned short (*)[32])(smem + 32768 + (b) * 8192))
  const int tid  = threadIdx.x;
  const int wid  = tid >> 6;
  const int lane = tid & 63;
  const int orig = blockIdx.x;

  if (orig >= 1024) {
    // ---- raw norms: 256 tail blocks x 8 waves x 16 rows (2-row batches)
    const int base_row = (orig - 1024) * 128 + wid * 16;
    for (int it = 0; it < 16; it += 2) {
      const float* s0p = raw + (size_t)(base_row + it) * Dv;
      const float* s1p = s0p + Dv;
      float4 v[2][3];
#pragma unroll
      for (int i = 0; i < 3; ++i)
        v[0][i] = reinterpret_cast<const float4*>(s0p)[i * 64 + lane];
#pragma unroll
      for (int i = 0; i < 3; ++i)
        v[1][i] = reinterpret_cast<const float4*>(s1p)[i * 64 + lane];
      float s[2];
#pragma unroll
      for (int r = 0; r < 2; ++r)
        s[r] = v[r][0].x * v[r][0].x + v[r][0].y * v[r][0].y + v[r][0].z * v[r][0].z + v[r][0].w * v[r][0].w
             + v[r][1].x * v[r][1].x + v[r][1].y * v[r][1].y + v[r][1].z * v[r][1].z + v[r][1].w * v[r][1].w
             + v[r][2].x * v[r][2].x + v[r][2].y * v[r][2].y + v[r][2].z * v[r][2].z + v[r][2].w * v[r][2].w;
#pragma unroll
      for (int off = 32; off > 0; off >>= 1) {
        s[0] += __shfl_xor(s[0], off);
        s[1] += __shfl_xor(s[1], off);
      }
      if (lane == 0) {
        inv_raw[base_row + it]     = 1.0f / fmaxf(sqrtf(s[0]), 1e-12f);
        inv_raw[base_row + it + 1] = 1.0f / fmaxf(sqrtf(s[1]), 1e-12f);
      }
    }
    return;
  }

  const int wm = wid >> 1, wn = wid & 1;
  // XCD swizzle: orig%8 = XCD; each XCD gets contiguous x-chunk, y fast
  const int wgid = ((orig & 7) << 7) | (orig >> 3);
  const int m0 = (wgid >> 3) * BM, n0 = (wgid & 7) * BN;
  const int fr = lane & 15;
  const int q  = lane >> 4;

  f32x4 acc[4][4];
#pragma unroll
  for (int i = 0; i < 4; ++i)
#pragma unroll
    for (int j = 0; j < 4; ++j)
#pragma unroll
      for (int r = 0; r < 4; ++r) acc[i][j][r] = 0.f;

  // staging source pointers (swizzled global source, linear LDS dest).
  // 64B rows, 4 slots, involution slot ^= (row>>1)&3 on source+read
  const int ra = wid * 16 + (lane >> 2);             // 0..127
  const int sa = (lane & 3) ^ ((ra >> 1) & 3);
  const unsigned short* srcA0 = Ah + (size_t)(m0 + ra) * Dv + sa * 8;
  const unsigned short* srcA1 = Ah + (size_t)(m0 + 128 + ra) * Dv + sa * 8;
  const unsigned short* srcB0 = Bh + (size_t)(n0 + ra) * Dv + sa * 8;

#define STG_A0(buf, t) __builtin_amdgcn_global_load_lds((g_u32*)(srcA0 + (t) * 32), \
    (l_u32*)&LA(buf)[wid * 16][0], 16, 0, 0)
#define STG_A1(buf, t) __builtin_amdgcn_global_load_lds((g_u32*)(srcA1 + (t) * 32), \
    (l_u32*)&LA(buf)[128 + wid * 16][0], 16, 0, 0)
#define STG_B0(buf, t) __builtin_amdgcn_global_load_lds((g_u32*)(srcB0 + (t) * 32), \
    (l_u32*)&LB(buf)[wid * 16][0], 16, 0, 0)

  const int slotR = (q ^ ((fr >> 1) & 3)) * 8;       // const per lane

  // prologue: tile 0 into buf 0 (3 loads/wave in flight)
  STG_A0(0, 0); STG_A1(0, 0); STG_B0(0, 0);

#pragma unroll 2
  for (int t = 0; t < 24; ++t) {
    const int cur = t & 1;
    // issue all 3 next-tile loads, then counted wait (they stay in flight)
    if (t < 23) {
      STG_A0(cur ^ 1, t + 1); STG_A1(cur ^ 1, t + 1); STG_B0(cur ^ 1, t + 1);
      asm volatile("s_waitcnt vmcnt(3)" ::: "memory");
    } else {
      asm volatile("s_waitcnt vmcnt(0)" ::: "memory");
    }
    __builtin_amdgcn_s_barrier();            // all waves' tile-t stage landed
    __builtin_amdgcn_sched_barrier(0);       // pin ds_reads below barrier

    bf16x8 a[4];
#pragma unroll
    for (int ph = 0; ph < 2; ++ph) {
      // ---- phase: ds-load subtile, fence, MFMA cluster, barrier ----
      if (ph == 0) {
#pragma unroll
        for (int i = 0; i < 4; ++i)
          a[i] = *reinterpret_cast<const bf16x8*>(&LA(cur)[wm * 64 + i * 16 + fr][slotR]);
      }
      bf16x8 b0 = *reinterpret_cast<const bf16x8*>(&LB(cur)[wn * 64 + (ph * 2) * 16 + fr][slotR]);
      bf16x8 b1 = *reinterpret_cast<const bf16x8*>(&LB(cur)[wn * 64 + (ph * 2 + 1) * 16 + fr][slotR]);
      asm volatile("s_waitcnt lgkmcnt(0)" ::: "memory");
      __builtin_amdgcn_sched_barrier(0);
      __builtin_amdgcn_s_setprio(1);
#pragma unroll
      for (int i = 0; i < 4; ++i) {
        acc[i][ph * 2]     = __builtin_amdgcn_mfma_f32_16x16x32_bf16(a[i], b0, acc[i][ph * 2], 0, 0, 0);
        acc[i][ph * 2 + 1] = __builtin_amdgcn_mfma_f32_16x16x32_bf16(a[i], b1, acc[i][ph * 2 + 1], 0, 0, 0);
      }
      __builtin_amdgcn_s_setprio(0);
      __builtin_amdgcn_sched_barrier(0);
      __builtin_amdgcn_s_barrier();          // phase boundary (wave lockstep)
      __builtin_amdgcn_sched_barrier(0);
    }
  }
#undef STG_A0
#undef STG_A1
#undef STG_B0

  // ---- column-max + atomics (register-only, before LDS reuse) ----
  const int b_img = m0 >> 10;
#pragma unroll
  for (int j = 0; j < 4; ++j) {
    int n = n0 + wn * 64 + j * 16 + fr;
    bool ok = (n < CKv);
    float cmax = -INFINITY;
#pragma unroll
    for (int i = 0; i < 4; ++i)
#pragma unroll
      for (int r = 0; r < 4; ++r) cmax = fmaxf(cmax, acc[i][j][r]);
    cmax = fmaxf(cmax, __shfl_xor(cmax, 16));
    cmax = fmaxf(cmax, __shfl_xor(cmax, 32));
    if (lane < 16 && ok)
      atomicMax(&iplU[(size_t)b_img * 1024 + n], fenc(cmax));
  }

  // ---- repack through LDS -> contiguous 512B row stores ----
  float (*ebuf)[132] = (float (*)[132])smem;   // 64 rows x 132 (pad) floats
  const int r2 = lane >> 5;                    // 0/1: row within pair
  const int cl = (lane & 31) * 4;              // col (floats)
#pragma unroll
  for (int p = 0; p < 4; ++p) {
    __syncthreads();                           // WAR vs previous pass readers
    if (wm == p) {
#pragma unroll
      for (int i = 0; i < 4; ++i)
#pragma unroll
        for (int j = 0; j < 4; ++j)
#pragma unroll
          for (int r = 0; r < 4; ++r)
            ebuf[i * 16 + q * 4 + r][wn * 64 + j * 16 + fr] = acc[i][j][r];
    }
    __syncthreads();
#pragma unroll
    for (int rr = 0; rr < 8; rr += 2) {
      int row = wid * 8 + rr + r2;
      f32x4 v = *reinterpret_cast<const f32x4*>(&ebuf[row][cl]);
      int gc = n0 + cl;
      size_t base = (size_t)(m0 + p * 64 + row) * CKv + gc;
      if (gc + 3 < CKv) {
        *reinterpret_cast<f32x4u*>(&Co[base]) = v;
      } else {
#pragma unroll
        for (int e = 0; e < 4; ++e)
          if (gc + e < CKv) Co[base + e] = v[e];
      }
    }
  }
#undef LA
#undef LB
}

// ---------- fused: per-chunk assign (inline softmax) + centroid accum + ipl
// grid (32 b, 3 d-chunks, 9): z<8 = 128-token chunks; z==8,y==0 = ipl finalize
__global__ __launch_bounds__(256) void accum_fused_kernel(
    const float* __restrict__ logits, const int* __restrict__ labels,
    const int* __restrict__ sam, const float* __restrict__ raw,
    const float* __restrict__ inv_raw, float* __restrict__ out,
    float* __restrict__ P_acc, int* __restrict__ present,
    const unsigned int* __restrict__ iplU, const float* __restrict__ sa_w) {
  const int b = blockIdx.x;
  const int y = blockIdx.y;
  const int z = blockIdx.z;
  if (z == 8) {
    if (y != 0) return;
    int c = threadIdx.x;
    if (c >= Cv) return;
    float r[Kv];
#pragma unroll
    for (int k = 0; k < Kv; ++k) {
      r[k] = fdec(iplU[(size_t)b * 1024 + c * Kv + k]);
      out[OFF_IPL + (size_t)(b * Cv + c) * Kv + k] = r[k];
    }
    if (c < NCLS) {
      float w[Kv], wm = -INFINITY;
#pragma unroll
      for (int k = 0; k < Kv; ++k) { w[k] = sa_w[c * Kv + k]; wm = fmaxf(wm, w[k]); }
      float es = 0.f;
#pragma unroll
      for (int k = 0; k < Kv; ++k) { w[k] = expf(w[k] - wm); es += w[k]; }
      float cl = 0.f;
#pragma unroll
      for (int k = 0; k < Kv; ++k) cl += r[k] * (w[k] / es * (float)Kv);
      out[OFF_CL + b * NCLS + c] = cl / 0.2f;
    }
    return;
  }

  __shared__ float As[128][Kv];
  __shared__ float Sc[128];
  __shared__ int   Ls[128];
  const int t0 = z * 128;
  if (threadIdx.x < 128) {
    int n = b * Nv + t0 + threadIdx.x;
    int lab = (sam[n] == 1) ? labels[b] : NCLS;
    const float* p = logits + (size_t)n * CKv + lab * Kv;
    float L[Kv];
#pragma unroll
    for (int k = 0; k < Kv; ++k) L[k] = p[k];
    float mv = L[0];
    int idx = 0;
#pragma unroll
    for (int k = 1; k < Kv; ++k)
      if (L[k] > mv) { mv = L[k]; idx = k; }
    float e[Kv], s = 0.f;
#pragma unroll
    for (int k = 0; k < Kv; ++k) { e[k] = expf(L[k] - mv); s += e[k]; }
    float inv = 1.0f / s;
    float scale = (inv < 0.8f) ? 0.f : inv;
#pragma unroll
    for (int k = 0; k < Kv; ++k) As[threadIdx.x][k] = e[k] * scale;
    Ls[threadIdx.x] = lab;
    Sc[threadIdx.x] = inv_raw[n];
    if (y == 0) {
      out[OFF_PSEUDO + n] = (float)lab;
      out[OFF_PART + n] = (float)(idx + lab * Kv);
      present[lab] = 1;
    }
  }
  __syncthreads();

  const int d = y * 256 + threadIdx.x;
  float accL[Kv] = {}, accB[Kv] = {};
#pragma unroll 4
  for (int t = 0; t < 128; ++t) {
    int n2 = b * Nv + t0 + t;
    float rv = raw[(size_t)n2 * Dv + d] * Sc[t];
    if (Ls[t] == NCLS) {
#pragma unroll
      for (int k = 0; k < Kv; ++k) accB[k] = fmaf(As[t][k], rv, accB[k]);
    } else {
#pragma unroll
      for (int k = 0; k < Kv; ++k) accL[k] = fmaf(As[t][k], rv, accL[k]);
    }
  }
  int lab = labels[b];
#pragma unroll
  for (int k = 0; k < Kv; ++k) atomicAdd(&P_acc[((size_t)lab * Kv + k) * Dv + d], accL[k]);
#pragma unroll
  for (int k = 0; k < Kv; ++k) atomicAdd(&P_acc[((size_t)NCLS * Kv + k) * Dv + d], accB[k]);
}

// ------------------------------------------------------------ EMA update
__global__ __launch_bounds__(256) void pnew_kernel(
    const float* __restrict__ proto, const float* __restrict__ P_acc,
    const int* __restrict__ present, float* __restrict__ out) {
  int i = blockIdx.x * 256 + threadIdx.x;
  if (i >= Cv * Kv * Dv) return;
  int c = i / (Kv * Dv);
  float p = proto[i];
  out[OFF_PNEW + i] = present[c] ? 0.999f * p + 0.001f * P_acc[i] : p;
}

// -------------------------------------------------------------- launcher
extern "C" void kernel_launch(void* const* d_in, const int* in_sizes, int n_in,
                              void* d_out, int out_size, void* d_ws, size_t ws_size,
                              hipStream_t stream) {
  const float* pt     = (const float*)d_in[0];
  const float* raw    = (const float*)d_in[1];
  const float* proto  = (const float*)d_in[2];
  const float* sa_w   = (const float*)d_in[3];
  const int*   labels = (const int*)d_in[4];
  const int*   sam    = (const int*)d_in[5];
  float* out = (float*)d_out;

  // ---- workspace layout ----
  float* A_buf   = (float*)d_ws;                           // kept for layout
  int*   tok_lab = (int*)(A_buf + (size_t)BNv * Kv);
  float* P_acc   = (float*)(tok_lab + BNv);                // 771840 f
  int*   present = (int*)(P_acc + (size_t)Cv * Kv * Dv);   // 256 i (pad)
  unsigned int* iplU = (unsigned int*)(present + 256);     // 32768 u
  float* inv_raw = (float*)(iplU + BNv);                   // 32768 f
  unsigned short* Ah = (unsigned short*)(inv_raw + BNv);   // 32768*768 us
  unsigned short* Bh = Ah + (size_t)BNv * Dv;              // 1024*768 us

  // zero region: P_acc + present + iplU (contiguous), fused into prep
  int nz = Cv * Kv * Dv + 256 + BNv;
  int ZB = (nz + 255) / 256;
  int prep_rows_blocks = (BNv + 1024) / 16;

  prep_kernel<<<ZB + prep_rows_blocks, 256, 0, stream>>>(
      pt, proto, Ah, Bh, (int*)P_acc, nz, ZB);

  // blocks [0,1024): GEMM; [1024,1280): raw-norm tail-fill
  gemm_mfma_kernel<<<1024 + 256, 512, 0, stream>>>(
      Ah, Bh, raw, inv_raw, out + OFF_LOG, iplU);

  accum_fused_kernel<<<dim3(Bv, Dv / 256, 9), 256, 0, stream>>>(
      out + OFF_LOG, labels, sam, raw, inv_raw, out, P_acc, present, iplU, sa_w);

  pnew_kernel<<<(Cv * Kv * Dv + 255) / 256, 256, 0, stream>>>(
      proto, P_acc, present, out);
}